// Round 5
// baseline (5973.273 us; speedup 1.0000x reference)
//
#include <hip/hip_runtime.h>

typedef unsigned int u32;
typedef unsigned short u16;
typedef _Float16 f16;
typedef f16 f16x2 __attribute__((ext_vector_type(2)));

__device__ __forceinline__ float fdot2(u32 a, u32 b, float c) {
#if __has_builtin(__builtin_amdgcn_fdot2)
    return __builtin_amdgcn_fdot2(__builtin_bit_cast(f16x2, a),
                                  __builtin_bit_cast(f16x2, b), c, false);
#else
    f16x2 av = __builtin_bit_cast(f16x2, a), bv = __builtin_bit_cast(f16x2, b);
    c += (float)av[0] * (float)bv[0];
    c += (float)av[1] * (float)bv[1];
    return c;
#endif
}

__device__ __forceinline__ u32 pack2h(float a, float b) {
    f16x2 h; h[0] = (f16)a; h[1] = (f16)b;
    return __builtin_bit_cast(u32, h);
}
__device__ __forceinline__ float h2f(u16 x) { return (float)__builtin_bit_cast(f16, x); }
__device__ __forceinline__ u16 f2h(float x) { f16 h = (f16)x; return __builtin_bit_cast(u16, h); }

__device__ __forceinline__ float fexp(float x) {
#if __has_builtin(__builtin_amdgcn_exp2f)
    return __builtin_amdgcn_exp2f(x * 1.44269504088896f);
#else
    return __expf(x);
#endif
}
__device__ __forceinline__ float frcp(float x) {
#if __has_builtin(__builtin_amdgcn_rcpf)
    return __builtin_amdgcn_rcpf(x);
#else
    return 1.0f / x;
#endif
}
__device__ __forceinline__ float fsigmoid(float x) { return frcp(1.0f + fexp(-x)); }
__device__ __forceinline__ float ftanh_pos(float x) { return 1.0f - 2.0f * frcp(fexp(2.0f * x) + 1.0f); }

template <int CTRL>
__device__ __forceinline__ float dpp_xor_add(float x) {
    int y = __builtin_amdgcn_update_dpp(0, __builtin_bit_cast(int, x), CTRL, 0xF, 0xF, true);
    return x + __builtin_bit_cast(float, y);
}

// ---------------------------------------------------------------------------
// K0: pack weights.
//   WpkT[d][p] = (Wi[d][2p], Wi[d][2p+1])   d<512, p<256
//   Wypk[p][d] = (Wy[d][2p], Wy[d][2p+1])
//   Wstr[t*20 + ...] : per-k2-thread streamed tail (5 uint4 cells, see k2 map)
// ---------------------------------------------------------------------------
__global__ __launch_bounds__(256) void k0_pack(const float* __restrict__ Wi,
                                               const float* __restrict__ Wy,
                                               u32* __restrict__ WpkT,
                                               u32* __restrict__ Wypk,
                                               u32* __restrict__ Wstr) {
    const int bx = blockIdx.x, tid = threadIdx.x;
    if (bx < 512) {
        const float2 v = *(const float2*)(Wi + (size_t)bx * 512 + 2 * tid);
        WpkT[(size_t)bx * 256 + tid] = pack2h(v.x, v.y);
    } else if (bx < 768) {
        const int p = bx - 512;
        #pragma unroll
        for (int r = 0; r < 2; ++r) {
            const int d = tid + 256 * r;
            Wypk[(size_t)p * 512 + d] =
                pack2h(Wy[(size_t)d * 512 + 2 * p], Wy[(size_t)d * 512 + 2 * p + 1]);
        }
    } else {
        // streamed cells for k2 thread t: sv0..sv2 = rows 4..6 pairs 60..63,
        // sv3 = row 7 pairs 56..59, sv4 = row 7 pairs 60..63 (local to kq)
        const int t = tid, dgk = t >> 2, kqk = t & 3;
        const int drow[5] = {4, 5, 6, 7, 7};
        const int cbas[5] = {60, 60, 60, 56, 60};
        #pragma unroll
        for (int m = 0; m < 5; ++m)
            #pragma unroll
            for (int q = 0; q < 4; ++q) {
                const int d = 8 * dgk + drow[m];
                const int p = 64 * kqk + cbas[m] + q;
                Wstr[t * 20 + 4 * m + q] = pack2h(Wi[(size_t)d * 512 + 2 * p],
                                                  Wi[(size_t)d * 512 + 2 * p + 1]);
            }
    }
}

// ---------------------------------------------------------------------------
// K1: gate pre-activations. Unchanged from round 4.
// ---------------------------------------------------------------------------
__global__ __launch_bounds__(256) void k1_gates(
    const float* __restrict__ word,
    const float* __restrict__ Wi, const float* __restrict__ Wz, const float* __restrict__ Wo,
    const float* __restrict__ bi, const float* __restrict__ bz, const float* __restrict__ bo,
    u16* __restrict__ Xi, u16* __restrict__ Xz, u16* __restrict__ Xo)
{
    __shared__ uint4 ws2v[3][128][4];
    __shared__ u32 xs2[2][16][36];

    const int tid = threadIdx.x;
    const int d_l = tid & 63;
    const int bq  = tid >> 6;
    const int t0  = blockIdx.x * 2;
    const int d0  = blockIdx.y * 128;

    const float* Wg[3] = {Wi, Wz, Wo};

    float acc[2][2][8][3];
    #pragma unroll
    for (int tt = 0; tt < 2; ++tt)
        #pragma unroll
        for (int db = 0; db < 2; ++db)
            #pragma unroll
            for (int j = 0; j < 8; ++j)
                #pragma unroll
                for (int g = 0; g < 3; ++g) acc[tt][db][j][g] = 0.0f;

    for (int k0c = 0; k0c < 512; k0c += 32) {
        {
            const int p = tid & 15, bg = tid >> 4;
            #pragma unroll
            for (int tt = 0; tt < 2; ++tt)
                #pragma unroll
                for (int j = 0; j < 2; ++j) {
                    const int bb = bg * 2 + j;
                    const float2 v = *(const float2*)(word + (((size_t)(t0 + tt) * 32 + bb) * 512 + k0c + 2 * p));
                    xs2[tt][p][bb] = pack2h(v.x, v.y);
                }
        }
        {
            #pragma unroll
            for (int cc = 0; cc < 6; ++cc) {
                const int c = tid + 256 * cc;
                const int g = c >> 9, r = c & 511, pg = r >> 7, i = r & 127;
                const float* src = Wg[g] + (size_t)(d0 + i) * 512 + k0c + 8 * pg;
                const float4 v0 = ((const float4*)src)[0];
                const float4 v1 = ((const float4*)src)[1];
                uint4 cell;
                cell.x = pack2h(v0.x, v0.y); cell.y = pack2h(v0.z, v0.w);
                cell.z = pack2h(v1.x, v1.y); cell.w = pack2h(v1.z, v1.w);
                ws2v[g][i][(pg + (i >> 2)) & 3] = cell;
            }
        }
        __syncthreads();
        #pragma unroll
        for (int pg = 0; pg < 4; ++pg) {
            uint4 wc[3][2];
            #pragma unroll
            for (int g = 0; g < 3; ++g)
                #pragma unroll
                for (int db = 0; db < 2; ++db) {
                    const int d = d_l + 64 * db;
                    wc[g][db] = ws2v[g][d][(pg + (d >> 2)) & 3];
                }
            #pragma unroll
            for (int p = 0; p < 4; ++p) {
                const int pair = 4 * pg + p;
                u32 x2[2][8];
                #pragma unroll
                for (int tt = 0; tt < 2; ++tt) {
                    const uint4* xr = (const uint4*)&xs2[tt][pair][bq * 8];
                    uint4 xa = xr[0], xb = xr[1];
                    x2[tt][0] = xa.x; x2[tt][1] = xa.y; x2[tt][2] = xa.z; x2[tt][3] = xa.w;
                    x2[tt][4] = xb.x; x2[tt][5] = xb.y; x2[tt][6] = xb.z; x2[tt][7] = xb.w;
                }
                u32 w[3][2];
                #pragma unroll
                for (int g = 0; g < 3; ++g)
                    #pragma unroll
                    for (int db = 0; db < 2; ++db) {
                        const uint4 v = wc[g][db];
                        w[g][db] = (p == 0) ? v.x : (p == 1) ? v.y : (p == 2) ? v.z : v.w;
                    }
                #pragma unroll
                for (int tt = 0; tt < 2; ++tt)
                    #pragma unroll
                    for (int db = 0; db < 2; ++db)
                        #pragma unroll
                        for (int j = 0; j < 8; ++j)
                            #pragma unroll
                            for (int g = 0; g < 3; ++g)
                                acc[tt][db][j][g] = fdot2(x2[tt][j], w[g][db], acc[tt][db][j][g]);
            }
        }
        __syncthreads();
    }

    #pragma unroll
    for (int db = 0; db < 2; ++db) {
        const int d = d0 + 64 * db + d_l;
        const float b0 = 2.0f * bi[d];
        const float b1 = bz[d] + bi[d];
        const float b2 = bo[d] + bi[d];
        #pragma unroll
        for (int tt = 0; tt < 2; ++tt)
            #pragma unroll
            for (int j = 0; j < 8; ++j) {
                const size_t o = ((size_t)(t0 + tt) * 32 + (bq * 8 + j)) * 512 + d;
                Xi[o] = f2h(acc[tt][db][j][0] + b0);
                Xz[o] = f2h(acc[tt][db][j][1] + b1);
                Xo[o] = f2h(acc[tt][db][j][2] + b2);
            }
    }
}

// ---------------------------------------------------------------------------
// K2 residency map (thread = (dg=tid>>2, kq=tid&3); 8 rows x 16 uint4 cells):
//   rows 0..3: cells 0..5 arch (24 u32), 6..13 AGPR (32), 14..15 LDS
//   rows 4..7: cells 0..4 arch (20 u32), 5..12 AGPR (32),
//              rows 4..6: 13..14 LDS, 15 stream; row 7: 13 LDS, 14..15 stream
// arch weights 176 + AGPR 256 + LDS 60 + stream 20 = 512 u32/thread.
// Zero scratch spill is the goal: arch demand ~231 < 256.
// ---------------------------------------------------------------------------
#define FOR8(M) M(0) M(1) M(2) M(3) M(4) M(5) M(6) M(7)

#define AGLIST(M, j) M(j,0) M(j,1) M(j,2) M(j,3) M(j,4) M(j,5) M(j,6) M(j,7) \
    M(j,8) M(j,9) M(j,10) M(j,11) M(j,12) M(j,13) M(j,14) M(j,15) M(j,16) M(j,17) \
    M(j,18) M(j,19) M(j,20) M(j,21) M(j,22) M(j,23) M(j,24) M(j,25) M(j,26) M(j,27) \
    M(j,28) M(j,29) M(j,30) M(j,31)
#define AG_DECL1(j,i) u32 ag##j##_##i;
#define AG_DECL_ROW(j) AGLIST(AG_DECL1, j)

#define AGW(j,i,v) asm volatile("v_accvgpr_write_b32 %0, %1" : "=a"(ag##j##_##i) : "v"(v));
#define AGR(d,j,i) asm volatile("v_accvgpr_read_b32 %0, %1" : "=v"(d) : "a"(ag##j##_##i));

// init rows 0..3: cells 0..5 -> wva[j][0..23]; 6..13 -> AGPR; 14,15 -> LDS
#define ROW_INIT_A(j) { \
    const uint4* rv = WpkT4 + (size_t)(8*dg + (j))*64 + 16*kq; uint4 r; \
    r = rv[6];  AGW(j,0,r.x)  AGW(j,1,r.y)  AGW(j,2,r.z)  AGW(j,3,r.w) \
    r = rv[7];  AGW(j,4,r.x)  AGW(j,5,r.y)  AGW(j,6,r.z)  AGW(j,7,r.w) \
    r = rv[8];  AGW(j,8,r.x)  AGW(j,9,r.y)  AGW(j,10,r.z) AGW(j,11,r.w) \
    r = rv[9];  AGW(j,12,r.x) AGW(j,13,r.y) AGW(j,14,r.z) AGW(j,15,r.w) \
    r = rv[10]; AGW(j,16,r.x) AGW(j,17,r.y) AGW(j,18,r.z) AGW(j,19,r.w) \
    r = rv[11]; AGW(j,20,r.x) AGW(j,21,r.y) AGW(j,22,r.z) AGW(j,23,r.w) \
    r = rv[12]; AGW(j,24,r.x) AGW(j,25,r.y) AGW(j,26,r.z) AGW(j,27,r.w) \
    r = rv[13]; AGW(j,28,r.x) AGW(j,29,r.y) AGW(j,30,r.z) AGW(j,31,r.w) \
    wld4st[2*(j)]   = rv[14]; \
    wld4st[2*(j)+1] = rv[15]; \
    r = rv[0]; wva[j][0] =r.x; wva[j][1] =r.y; wva[j][2] =r.z; wva[j][3] =r.w; \
    r = rv[1]; wva[j][4] =r.x; wva[j][5] =r.y; wva[j][6] =r.z; wva[j][7] =r.w; \
    r = rv[2]; wva[j][8] =r.x; wva[j][9] =r.y; wva[j][10]=r.z; wva[j][11]=r.w; \
    r = rv[3]; wva[j][12]=r.x; wva[j][13]=r.y; wva[j][14]=r.z; wva[j][15]=r.w; \
    r = rv[4]; wva[j][16]=r.x; wva[j][17]=r.y; wva[j][18]=r.z; wva[j][19]=r.w; \
    r = rv[5]; wva[j][20]=r.x; wva[j][21]=r.y; wva[j][22]=r.z; wva[j][23]=r.w; \
}

// init rows 4..6: cells 0..4 -> wvb[j-4][0..19]; 5..12 -> AGPR; 13,14 -> LDS
#define ROW_INIT_B(j) { \
    const uint4* rv = WpkT4 + (size_t)(8*dg + (j))*64 + 16*kq; uint4 r; \
    r = rv[5];  AGW(j,0,r.x)  AGW(j,1,r.y)  AGW(j,2,r.z)  AGW(j,3,r.w) \
    r = rv[6];  AGW(j,4,r.x)  AGW(j,5,r.y)  AGW(j,6,r.z)  AGW(j,7,r.w) \
    r = rv[7];  AGW(j,8,r.x)  AGW(j,9,r.y)  AGW(j,10,r.z) AGW(j,11,r.w) \
    r = rv[8];  AGW(j,12,r.x) AGW(j,13,r.y) AGW(j,14,r.z) AGW(j,15,r.w) \
    r = rv[9];  AGW(j,16,r.x) AGW(j,17,r.y) AGW(j,18,r.z) AGW(j,19,r.w) \
    r = rv[10]; AGW(j,20,r.x) AGW(j,21,r.y) AGW(j,22,r.z) AGW(j,23,r.w) \
    r = rv[11]; AGW(j,24,r.x) AGW(j,25,r.y) AGW(j,26,r.z) AGW(j,27,r.w) \
    r = rv[12]; AGW(j,28,r.x) AGW(j,29,r.y) AGW(j,30,r.z) AGW(j,31,r.w) \
    wld4st[8+2*((j)-4)] = rv[13]; \
    wld4st[9+2*((j)-4)] = rv[14]; \
    r = rv[0]; wvb[(j)-4][0] =r.x; wvb[(j)-4][1] =r.y; wvb[(j)-4][2] =r.z; wvb[(j)-4][3] =r.w; \
    r = rv[1]; wvb[(j)-4][4] =r.x; wvb[(j)-4][5] =r.y; wvb[(j)-4][6] =r.z; wvb[(j)-4][7] =r.w; \
    r = rv[2]; wvb[(j)-4][8] =r.x; wvb[(j)-4][9] =r.y; wvb[(j)-4][10]=r.z; wvb[(j)-4][11]=r.w; \
    r = rv[3]; wvb[(j)-4][12]=r.x; wvb[(j)-4][13]=r.y; wvb[(j)-4][14]=r.z; wvb[(j)-4][15]=r.w; \
    r = rv[4]; wvb[(j)-4][16]=r.x; wvb[(j)-4][17]=r.y; wvb[(j)-4][18]=r.z; wvb[(j)-4][19]=r.w; \
}

// init row 7: cells 0..4 -> wvb[3]; 5..12 -> AGPR; 13 -> LDS; 14,15 streamed
#define ROW_INIT_B7 { \
    const uint4* rv = WpkT4 + (size_t)(8*dg + 7)*64 + 16*kq; uint4 r; \
    r = rv[5];  AGW(7,0,r.x)  AGW(7,1,r.y)  AGW(7,2,r.z)  AGW(7,3,r.w) \
    r = rv[6];  AGW(7,4,r.x)  AGW(7,5,r.y)  AGW(7,6,r.z)  AGW(7,7,r.w) \
    r = rv[7];  AGW(7,8,r.x)  AGW(7,9,r.y)  AGW(7,10,r.z) AGW(7,11,r.w) \
    r = rv[8];  AGW(7,12,r.x) AGW(7,13,r.y) AGW(7,14,r.z) AGW(7,15,r.w) \
    r = rv[9];  AGW(7,16,r.x) AGW(7,17,r.y) AGW(7,18,r.z) AGW(7,19,r.w) \
    r = rv[10]; AGW(7,20,r.x) AGW(7,21,r.y) AGW(7,22,r.z) AGW(7,23,r.w) \
    r = rv[11]; AGW(7,24,r.x) AGW(7,25,r.y) AGW(7,26,r.z) AGW(7,27,r.w) \
    r = rv[12]; AGW(7,28,r.x) AGW(7,29,r.y) AGW(7,30,r.z) AGW(7,31,r.w) \
    wld4st[14] = rv[13]; \
    r = rv[0]; wvb[3][0] =r.x; wvb[3][1] =r.y; wvb[3][2] =r.z; wvb[3][3] =r.w; \
    r = rv[1]; wvb[3][4] =r.x; wvb[3][5] =r.y; wvb[3][6] =r.z; wvb[3][7] =r.w; \
    r = rv[2]; wvb[3][8] =r.x; wvb[3][9] =r.y; wvb[3][10]=r.z; wvb[3][11]=r.w; \
    r = rv[3]; wvb[3][12]=r.x; wvb[3][13]=r.y; wvb[3][14]=r.z; wvb[3][15]=r.w; \
    r = rv[4]; wvb[3][16]=r.x; wvb[3][17]=r.y; wvb[3][18]=r.z; wvb[3][19]=r.w; \
}

#define VD(j, e0,e1,e2,e3) \
    acc[j] = fdot2(hc.x, (e0), acc[j]); acc[j] = fdot2(hc.y, (e1), acc[j]); \
    acc[j] = fdot2(hc.z, (e2), acc[j]); acc[j] = fdot2(hc.w, (e3), acc[j]);
#define VDW(j, arr, c) VD(j, arr[4*(c)+0], arr[4*(c)+1], arr[4*(c)+2], arr[4*(c)+3])
#define VDL(j, slot) { const uint4 L = wld4[slot]; VD(j, L.x, L.y, L.z, L.w) }
#define VDS(j, sv) VD(j, (sv).x, (sv).y, (sv).z, (sv).w)
#define VDA(j, i0,i1,i2,i3) { u32 t0,t1,t2,t3; \
    AGR(t0,j,i0) AGR(t1,j,i1) AGR(t2,j,i2) AGR(t3,j,i3) VD(j, t0,t1,t2,t3) }

#define CELLV(c) { hc = hv[c]; \
    VDW(0, wva[0], c) VDW(1, wva[1], c) VDW(2, wva[2], c) VDW(3, wva[3], c) \
    VDW(4, wvb[0], c) VDW(5, wvb[1], c) VDW(6, wvb[2], c) VDW(7, wvb[3], c) }

__global__ __launch_bounds__(256, 1) void k2_recur(
    const u16* __restrict__ Xi, const u16* __restrict__ Xz, const u16* __restrict__ Xo,
    const u32* __restrict__ WpkT, const u32* __restrict__ Wypk,
    const u32* __restrict__ Wstr,
    const float* __restrict__ by, float* __restrict__ out)
{
    __shared__ alignas(16) uint4 wldsv[256 * 15];   // 61440 B
    __shared__ alignas(16) u16 hbuf[2][4 * 144];    // 288B-stride quarters, 2304 B

    const int b   = blockIdx.x;
    const int tid = threadIdx.x;
    const int kq  = tid & 3;
    const int dg  = tid >> 2;

    const uint4* WpkT4 = (const uint4*)WpkT;
    uint4* wld4st = wldsv + tid * 15;
    const uint4* wld4 = wldsv + tid * 15;

    u32 wva[4][24];
    u32 wvb[4][20];
    FOR8(AG_DECL_ROW)
    ROW_INIT_A(0) ROW_INIT_A(1) ROW_INIT_A(2) ROW_INIT_A(3)
    ROW_INIT_B(4) ROW_INIT_B(5) ROW_INIT_B(6) ROW_INIT_B7

    const int d0 = 8 * dg + 2 * kq;
    const int hq_ = d0 >> 7, hj_ = d0 & 127;
    u32* hw0 = (u32*)((char*)&hbuf[0][0] + hq_ * 288 + 2 * hj_);
    u32* hw1 = (u32*)((char*)&hbuf[1][0] + hq_ * 288 + 2 * hj_);
    *hw0 = 0u;
    __syncthreads();

    const uint4* hv0 = (const uint4*)((const char*)&hbuf[0][0] + kq * 288);
    const uint4* hv1 = (const uint4*)((const char*)&hbuf[1][0] + kq * 288);
    const uint4* Wstr4 = (const uint4*)(Wstr + tid * 20);

    u32 xi_c = *(const u32*)(Xi + (size_t)b * 512 + d0);
    u32 xz_c = *(const u32*)(Xz + (size_t)b * 512 + d0);
    u32 xo_c = *(const u32*)(Xo + (size_t)b * 512 + d0);

    for (int t = 0; t < 2048; ++t) {
        const int cur = t & 1;
        // L2-hot streamed weights + next-X, issued at loop top (latency hidden)
        const uint4 sv0 = Wstr4[0], sv1 = Wstr4[1], sv2 = Wstr4[2];
        const uint4 sv3 = Wstr4[3], sv4 = Wstr4[4];
        const int tn = (t + 1) & 2047;
        const size_t xbase = ((size_t)tn * 32 + b) * 512 + d0;
        const u32 xi_n = *(const u32*)(Xi + xbase);
        const u32 xz_n = *(const u32*)(Xz + xbase);
        const u32 xo_n = *(const u32*)(Xo + xbase);

        const uint4* hv = cur ? hv1 : hv0;
        float acc[8] = {0.f, 0.f, 0.f, 0.f, 0.f, 0.f, 0.f, 0.f};
        uint4 hc;

        CELLV(0) CELLV(1) CELLV(2) CELLV(3) CELLV(4)
        hc = hv[5];
        VDW(0, wva[0], 5) VDW(1, wva[1], 5) VDW(2, wva[2], 5) VDW(3, wva[3], 5)
        VDA(4, 0,1,2,3) VDA(5, 0,1,2,3) VDA(6, 0,1,2,3) VDA(7, 0,1,2,3)
        hc = hv[6];
        VDA(0, 0,1,2,3)     VDA(1, 0,1,2,3)     VDA(2, 0,1,2,3)     VDA(3, 0,1,2,3)
        VDA(4, 4,5,6,7)     VDA(5, 4,5,6,7)     VDA(6, 4,5,6,7)     VDA(7, 4,5,6,7)
        hc = hv[7];
        VDA(0, 4,5,6,7)     VDA(1, 4,5,6,7)     VDA(2, 4,5,6,7)     VDA(3, 4,5,6,7)
        VDA(4, 8,9,10,11)   VDA(5, 8,9,10,11)   VDA(6, 8,9,10,11)   VDA(7, 8,9,10,11)
        hc = hv[8];
        VDA(0, 8,9,10,11)   VDA(1, 8,9,10,11)   VDA(2, 8,9,10,11)   VDA(3, 8,9,10,11)
        VDA(4, 12,13,14,15) VDA(5, 12,13,14,15) VDA(6, 12,13,14,15) VDA(7, 12,13,14,15)
        hc = hv[9];
        VDA(0, 12,13,14,15) VDA(1, 12,13,14,15) VDA(2, 12,13,14,15) VDA(3, 12,13,14,15)
        VDA(4, 16,17,18,19) VDA(5, 16,17,18,19) VDA(6, 16,17,18,19) VDA(7, 16,17,18,19)
        hc = hv[10];
        VDA(0, 16,17,18,19) VDA(1, 16,17,18,19) VDA(2, 16,17,18,19) VDA(3, 16,17,18,19)
        VDA(4, 20,21,22,23) VDA(5, 20,21,22,23) VDA(6, 20,21,22,23) VDA(7, 20,21,22,23)
        hc = hv[11];
        VDA(0, 20,21,22,23) VDA(1, 20,21,22,23) VDA(2, 20,21,22,23) VDA(3, 20,21,22,23)
        VDA(4, 24,25,26,27) VDA(5, 24,25,26,27) VDA(6, 24,25,26,27) VDA(7, 24,25,26,27)
        hc = hv[12];
        VDA(0, 24,25,26,27) VDA(1, 24,25,26,27) VDA(2, 24,25,26,27) VDA(3, 24,25,26,27)
        VDA(4, 28,29,30,31) VDA(5, 28,29,30,31) VDA(6, 28,29,30,31) VDA(7, 28,29,30,31)
        hc = hv[13];
        VDA(0, 28,29,30,31) VDA(1, 28,29,30,31) VDA(2, 28,29,30,31) VDA(3, 28,29,30,31)
        VDL(4, 8) VDL(5, 10) VDL(6, 12) VDL(7, 14)
        hc = hv[14];
        VDL(0, 0) VDL(1, 2) VDL(2, 4) VDL(3, 6)
        VDL(4, 9) VDL(5, 11) VDL(6, 13) VDS(7, sv3)
        hc = hv[15];
        VDL(0, 1) VDL(1, 3) VDL(2, 5) VDL(3, 7)
        VDS(4, sv0) VDS(5, sv1) VDS(6, sv2) VDS(7, sv4)

        // quad butterfly: every lane gets all 8 full sums
        #pragma unroll
        for (int j = 0; j < 8; ++j) acc[j] = dpp_xor_add<0xB1>(acc[j]);
        #pragma unroll
        for (int j = 0; j < 8; ++j) acc[j] = dpp_xor_add<0x4E>(acc[j]);

        const float v0 = (kq & 2) ? ((kq & 1) ? acc[6] : acc[4]) : ((kq & 1) ? acc[2] : acc[0]);
        const float v1 = (kq & 2) ? ((kq & 1) ? acc[7] : acc[5]) : ((kq & 1) ? acc[3] : acc[1]);

        const f16x2 xi2 = __builtin_bit_cast(f16x2, xi_c);
        const f16x2 xz2 = __builtin_bit_cast(f16x2, xz_c);
        const f16x2 xo2 = __builtin_bit_cast(f16x2, xo_c);

        const float zi0 = fsigmoid((float)xi2[0] + v0);
        const float z0  = fsigmoid((float)xz2[0] + v0);
        const float zo0 = fsigmoid((float)xo2[0] + v0);
        const float hn0 = zo0 * ftanh_pos(zi0 * z0);
        const float zi1 = fsigmoid((float)xi2[1] + v1);
        const float z1  = fsigmoid((float)xz2[1] + v1);
        const float zo1 = fsigmoid((float)xo2[1] + v1);
        const float hn1 = zo1 * ftanh_pos(zi1 * z1);

        const u32 hwv = (u32)f2h(hn0) | ((u32)f2h(hn1) << 16);
        *(cur ? hw0 : hw1) = hwv;
        __syncthreads();

        xi_c = xi_n; xz_c = xz_n; xo_c = xo_n;
    }

    // epilogue: final h in hbuf[0]; out[b, d] = h @ Wy.T + by for d=tid, tid+256
    {
        float e0 = 0.f, e1 = 0.f;
        #pragma unroll
        for (int q = 0; q < 4; ++q) {
            const uint4* hq = (const uint4*)((const char*)&hbuf[0][0] + q * 288);
            #pragma unroll
            for (int i = 0; i < 16; ++i) {
                uint4 hc = hq[i];
                const int p = 64 * q + 4 * i;
                e0 = fdot2(hc.x, Wypk[(size_t)(p + 0) * 512 + tid], e0);
                e0 = fdot2(hc.y, Wypk[(size_t)(p + 1) * 512 + tid], e0);
                e0 = fdot2(hc.z, Wypk[(size_t)(p + 2) * 512 + tid], e0);
                e0 = fdot2(hc.w, Wypk[(size_t)(p + 3) * 512 + tid], e0);
                e1 = fdot2(hc.x, Wypk[(size_t)(p + 0) * 512 + tid + 256], e1);
                e1 = fdot2(hc.y, Wypk[(size_t)(p + 1) * 512 + tid + 256], e1);
                e1 = fdot2(hc.z, Wypk[(size_t)(p + 2) * 512 + tid + 256], e1);
                e1 = fdot2(hc.w, Wypk[(size_t)(p + 3) * 512 + tid + 256], e1);
            }
        }
        out[(size_t)b * 512 + tid]       = e0 + by[tid];
        out[(size_t)b * 512 + tid + 256] = e1 + by[tid + 256];
    }
}

// ---------------------------------------------------------------------------
extern "C" void kernel_launch(void* const* d_in, const int* in_sizes, int n_in,
                              void* d_out, int out_size, void* d_ws, size_t ws_size,
                              hipStream_t stream) {
    const float* word = (const float*)d_in[0];
    // d_in[1]=Wf, d_in[2]=bf : dead in the reference (c==0 path), unused.
    const float* Wi = (const float*)d_in[3];
    const float* bi = (const float*)d_in[4];
    const float* Wz = (const float*)d_in[5];
    const float* bz = (const float*)d_in[6];
    const float* Wo = (const float*)d_in[7];
    const float* bo = (const float*)d_in[8];
    const float* Wy = (const float*)d_in[9];
    const float* by = (const float*)d_in[10];
    float* out = (float*)d_out;

    char* ws = (char*)d_ws;
    const size_t XN = (size_t)2048 * 32 * 512 * sizeof(u16);  // 64 MB per gate array
    u16* Xi = (u16*)(ws);
    u16* Xz = (u16*)(ws + XN);
    u16* Xo = (u16*)(ws + 2 * XN);
    u32* WpkT = (u32*)(ws + 3 * XN);                            // 512 KB
    u32* Wypk = (u32*)(ws + 3 * XN + (size_t)524288);           // 512 KB
    u32* Wstr = (u32*)(ws + 3 * XN + (size_t)2 * 524288);       // 20 KB

    k0_pack<<<769, 256, 0, stream>>>(Wi, Wy, WpkT, Wypk, Wstr);

    dim3 g1(1024, 4);
    k1_gates<<<g1, 256, 0, stream>>>(word, Wi, Wz, Wo, bi, bz, bo, Xi, Xz, Xo);

    k2_recur<<<32, 256, 0, stream>>>(Xi, Xz, Xo, WpkT, Wypk, Wstr, by, out);
}

// Round 6
// 4449.121 us; speedup vs baseline: 1.3426x; 1.3426x over previous
//
#include <hip/hip_runtime.h>

typedef unsigned int u32;
typedef unsigned short u16;
typedef unsigned long long u64;
typedef _Float16 f16;
typedef f16 f16x2 __attribute__((ext_vector_type(2)));

__device__ __forceinline__ float fdot2(u32 a, u32 b, float c) {
#if __has_builtin(__builtin_amdgcn_fdot2)
    return __builtin_amdgcn_fdot2(__builtin_bit_cast(f16x2, a),
                                  __builtin_bit_cast(f16x2, b), c, false);
#else
    f16x2 av = __builtin_bit_cast(f16x2, a), bv = __builtin_bit_cast(f16x2, b);
    c += (float)av[0] * (float)bv[0];
    c += (float)av[1] * (float)bv[1];
    return c;
#endif
}

__device__ __forceinline__ u32 pack2h(float a, float b) {
    f16x2 h; h[0] = (f16)a; h[1] = (f16)b;
    return __builtin_bit_cast(u32, h);
}
__device__ __forceinline__ float h2f(u16 x) { return (float)__builtin_bit_cast(f16, x); }
__device__ __forceinline__ u16 f2h(float x) { f16 h = (f16)x; return __builtin_bit_cast(u16, h); }

__device__ __forceinline__ float fexp(float x) {
#if __has_builtin(__builtin_amdgcn_exp2f)
    return __builtin_amdgcn_exp2f(x * 1.44269504088896f);
#else
    return __expf(x);
#endif
}
__device__ __forceinline__ float frcp(float x) {
#if __has_builtin(__builtin_amdgcn_rcpf)
    return __builtin_amdgcn_rcpf(x);
#else
    return 1.0f / x;
#endif
}
__device__ __forceinline__ float fsigmoid(float x) { return frcp(1.0f + fexp(-x)); }
__device__ __forceinline__ float ftanh_pos(float x) { return 1.0f - 2.0f * frcp(fexp(2.0f * x) + 1.0f); }

// ---------------------------------------------------------------------------
// K0: pack weights to f16 pairs.
//   WpkT[d][p] = (Wi[d][2p], Wi[d][2p+1])   d<512, p<256   (row-major rows)
//   Wypk[p][d] = (Wy[d][2p], Wy[d][2p+1])   (K2 epilogue layout)
// ---------------------------------------------------------------------------
__global__ __launch_bounds__(256) void k0_pack(const float* __restrict__ Wi,
                                               const float* __restrict__ Wy,
                                               u32* __restrict__ WpkT,
                                               u32* __restrict__ Wypk) {
    const int bx = blockIdx.x, tid = threadIdx.x;
    if (bx < 512) {
        const float2 v = *(const float2*)(Wi + (size_t)bx * 512 + 2 * tid);
        WpkT[(size_t)bx * 256 + tid] = pack2h(v.x, v.y);
    } else {
        const int p = bx - 512;
        #pragma unroll
        for (int r = 0; r < 2; ++r) {
            const int d = tid + 256 * r;
            Wypk[(size_t)p * 512 + d] =
                pack2h(Wy[(size_t)d * 512 + 2 * p], Wy[(size_t)d * 512 + 2 * p + 1]);
        }
    }
}

// ---------------------------------------------------------------------------
// K1: gate pre-activations (parallel over all t). Unchanged from round 5.
// ---------------------------------------------------------------------------
__global__ __launch_bounds__(256) void k1_gates(
    const float* __restrict__ word,
    const float* __restrict__ Wi, const float* __restrict__ Wz, const float* __restrict__ Wo,
    const float* __restrict__ bi, const float* __restrict__ bz, const float* __restrict__ bo,
    u16* __restrict__ Xi, u16* __restrict__ Xz, u16* __restrict__ Xo)
{
    __shared__ uint4 ws2v[3][128][4];
    __shared__ u32 xs2[2][16][36];

    const int tid = threadIdx.x;
    const int d_l = tid & 63;
    const int bq  = tid >> 6;
    const int t0  = blockIdx.x * 2;
    const int d0  = blockIdx.y * 128;

    const float* Wg[3] = {Wi, Wz, Wo};

    float acc[2][2][8][3];
    #pragma unroll
    for (int tt = 0; tt < 2; ++tt)
        #pragma unroll
        for (int db = 0; db < 2; ++db)
            #pragma unroll
            for (int j = 0; j < 8; ++j)
                #pragma unroll
                for (int g = 0; g < 3; ++g) acc[tt][db][j][g] = 0.0f;

    for (int k0c = 0; k0c < 512; k0c += 32) {
        {
            const int p = tid & 15, bg = tid >> 4;
            #pragma unroll
            for (int tt = 0; tt < 2; ++tt)
                #pragma unroll
                for (int j = 0; j < 2; ++j) {
                    const int bb = bg * 2 + j;
                    const float2 v = *(const float2*)(word + (((size_t)(t0 + tt) * 32 + bb) * 512 + k0c + 2 * p));
                    xs2[tt][p][bb] = pack2h(v.x, v.y);
                }
        }
        {
            #pragma unroll
            for (int cc = 0; cc < 6; ++cc) {
                const int c = tid + 256 * cc;
                const int g = c >> 9, r = c & 511, pg = r >> 7, i = r & 127;
                const float* src = Wg[g] + (size_t)(d0 + i) * 512 + k0c + 8 * pg;
                const float4 v0 = ((const float4*)src)[0];
                const float4 v1 = ((const float4*)src)[1];
                uint4 cell;
                cell.x = pack2h(v0.x, v0.y); cell.y = pack2h(v0.z, v0.w);
                cell.z = pack2h(v1.x, v1.y); cell.w = pack2h(v1.z, v1.w);
                ws2v[g][i][(pg + (i >> 2)) & 3] = cell;
            }
        }
        __syncthreads();
        #pragma unroll
        for (int pg = 0; pg < 4; ++pg) {
            uint4 wc[3][2];
            #pragma unroll
            for (int g = 0; g < 3; ++g)
                #pragma unroll
                for (int db = 0; db < 2; ++db) {
                    const int d = d_l + 64 * db;
                    wc[g][db] = ws2v[g][d][(pg + (d >> 2)) & 3];
                }
            #pragma unroll
            for (int p = 0; p < 4; ++p) {
                const int pair = 4 * pg + p;
                u32 x2[2][8];
                #pragma unroll
                for (int tt = 0; tt < 2; ++tt) {
                    const uint4* xr = (const uint4*)&xs2[tt][pair][bq * 8];
                    uint4 xa = xr[0], xb = xr[1];
                    x2[tt][0] = xa.x; x2[tt][1] = xa.y; x2[tt][2] = xa.z; x2[tt][3] = xa.w;
                    x2[tt][4] = xb.x; x2[tt][5] = xb.y; x2[tt][6] = xb.z; x2[tt][7] = xb.w;
                }
                u32 w[3][2];
                #pragma unroll
                for (int g = 0; g < 3; ++g)
                    #pragma unroll
                    for (int db = 0; db < 2; ++db) {
                        const uint4 v = wc[g][db];
                        w[g][db] = (p == 0) ? v.x : (p == 1) ? v.y : (p == 2) ? v.z : v.w;
                    }
                #pragma unroll
                for (int tt = 0; tt < 2; ++tt)
                    #pragma unroll
                    for (int db = 0; db < 2; ++db)
                        #pragma unroll
                        for (int j = 0; j < 8; ++j)
                            #pragma unroll
                            for (int g = 0; g < 3; ++g)
                                acc[tt][db][j][g] = fdot2(x2[tt][j], w[g][db], acc[tt][db][j][g]);
            }
        }
        __syncthreads();
    }

    #pragma unroll
    for (int db = 0; db < 2; ++db) {
        const int d = d0 + 64 * db + d_l;
        const float b0 = 2.0f * bi[d];
        const float b1 = bz[d] + bi[d];
        const float b2 = bo[d] + bi[d];
        #pragma unroll
        for (int tt = 0; tt < 2; ++tt)
            #pragma unroll
            for (int j = 0; j < 8; ++j) {
                const size_t o = ((size_t)(t0 + tt) * 32 + (bq * 8 + j)) * 512 + d;
                Xi[o] = f2h(acc[tt][db][j][0] + b0);
                Xz[o] = f2h(acc[tt][db][j][1] + b1);
                Xo[o] = f2h(acc[tt][db][j][2] + b2);
            }
    }
}

// ---------------------------------------------------------------------------
// K2 v2: K-split recurrence. TWO workgroups per batch element:
//   WG(b,half) holds the weight slice for K-pairs [128*half, 128*half+128)
//   for ALL 512 outputs: thread tid = output d, 32 uint4 = 128 u32 in VGPRs.
//   (256 KB/CU = half the weights -> fits arch VGPRs at 2 waves/SIMD, no spill.)
// Per step: thread computes partial dot p over its K-half from own-half h in
// LDS (broadcast b128 reads), exchanges {p, tag=t+1} with the partner WG via
// one IC-coherent 8-byte atomic store/load (tag rides with data -> no fences,
// no L2 flush). v = p + p_partner -> gates -> h_new; own-half threads store
// h to LDS ping-pong. One barrier/step. Poisoned tags (0xAAAAAAAA) never
// match t+1 in [1,2048], so no exchange-buffer init is needed.
// Epilogue: both WGs build full h in LDS and redundantly compute identical
// out[b,:] (benign duplicate stores).
// ---------------------------------------------------------------------------
__global__ __launch_bounds__(512, 1) void k2_recur(
    const u16* __restrict__ Xi, const u16* __restrict__ Xz, const u16* __restrict__ Xo,
    const u32* __restrict__ WpkT, const u32* __restrict__ Wypk,
    u64* __restrict__ exch,
    const float* __restrict__ by, float* __restrict__ out)
{
    __shared__ alignas(16) u16 hb[2][256];   // own K-half of h, f16, ping-pong
    __shared__ alignas(16) u16 hfull[512];   // final h for the epilogue

    const int bid  = blockIdx.x;
    const int b    = bid >> 1;
    const int half = bid & 1;
    const int tid  = threadIdx.x;            // = output dim d

    // weight slice: 32 uint4 per thread (output d=tid, K-pairs 128*half+4i..)
    const uint4* WpkT4 = (const uint4*)WpkT;
    uint4 w[32];
    #pragma unroll
    for (int i = 0; i < 32; ++i) w[i] = WpkT4[(size_t)tid * 64 + half * 32 + i];

    if (tid < 256) hb[0][tid] = (u16)0;      // h = 0 at t = 0
    __syncthreads();

    u64* eo = exch + ((size_t)(b * 2 + half) * 2) * 512 + tid;
    const u64* ei = exch + ((size_t)(b * 2 + (half ^ 1)) * 2) * 512 + tid;

    const int ownhalf = ((tid >> 8) == half);
    const int hloc = tid & 255;

    // prefetch X for t=0
    u16 xi_c = Xi[(size_t)b * 512 + tid];
    u16 xz_c = Xz[(size_t)b * 512 + tid];
    u16 xo_c = Xo[(size_t)b * 512 + tid];

    float hn = 0.0f;
    for (int t = 0; t < 2048; ++t) {
        const int par = t & 1;
        const int tn = (t + 1) & 2047;
        const size_t xb = ((size_t)tn * 32 + b) * 512 + tid;
        const u16 xi_n = Xi[xb], xz_n = Xz[xb], xo_n = Xo[xb];

        // partial dot over own K-half (h broadcast from LDS)
        const uint4* hv = (const uint4*)&hb[par][0];
        float a0 = 0.f, a1 = 0.f, a2 = 0.f, a3 = 0.f;
        #pragma unroll
        for (int i = 0; i < 32; ++i) {
            const uint4 hc = hv[i];
            a0 = fdot2(hc.x, w[i].x, a0);
            a1 = fdot2(hc.y, w[i].y, a1);
            a2 = fdot2(hc.z, w[i].z, a2);
            a3 = fdot2(hc.w, w[i].w, a3);
        }
        const float p = (a0 + a1) + (a2 + a3);

        // post {p, tag} to partner; poll partner's slot (single 8B coherent op)
        const u64 msg = ((u64)(u32)(t + 1) << 32) | (u64)__builtin_bit_cast(u32, p);
        __hip_atomic_store(eo + (size_t)par * 512, msg,
                           __ATOMIC_RELAXED, __HIP_MEMORY_SCOPE_AGENT);
        u64 m;
        do {
            m = __hip_atomic_load(ei + (size_t)par * 512,
                                  __ATOMIC_RELAXED, __HIP_MEMORY_SCOPE_AGENT);
        } while ((u32)(m >> 32) != (u32)(t + 1));
        const float v = p + __builtin_bit_cast(float, (u32)m);

        // gates for output d = tid
        const float zi = fsigmoid(h2f(xi_c) + v);
        const float z  = fsigmoid(h2f(xz_c) + v);
        const float zo = fsigmoid(h2f(xo_c) + v);
        hn = zo * ftanh_pos(zi * z);

        if (ownhalf) hb[par ^ 1][hloc] = f2h(hn);
        __syncthreads();

        xi_c = xi_n; xz_c = xz_n; xo_c = xo_n;
    }

    // epilogue: both WGs redundantly compute identical out[b,:]
    hfull[tid] = f2h(hn);
    __syncthreads();
    {
        const uint4* hv = (const uint4*)&hfull[0];
        float e0 = 0.f, e1 = 0.f, e2 = 0.f, e3 = 0.f;
        #pragma unroll 8
        for (int i = 0; i < 64; ++i) {
            const uint4 hc = hv[i];
            e0 = fdot2(hc.x, Wypk[(size_t)(4 * i + 0) * 512 + tid], e0);
            e1 = fdot2(hc.y, Wypk[(size_t)(4 * i + 1) * 512 + tid], e1);
            e2 = fdot2(hc.z, Wypk[(size_t)(4 * i + 2) * 512 + tid], e2);
            e3 = fdot2(hc.w, Wypk[(size_t)(4 * i + 3) * 512 + tid], e3);
        }
        out[(size_t)b * 512 + tid] = (e0 + e1) + (e2 + e3) + by[tid];
    }
}

// ---------------------------------------------------------------------------
extern "C" void kernel_launch(void* const* d_in, const int* in_sizes, int n_in,
                              void* d_out, int out_size, void* d_ws, size_t ws_size,
                              hipStream_t stream) {
    const float* word = (const float*)d_in[0];
    // d_in[1]=Wf, d_in[2]=bf : dead in the reference (c==0 path), unused.
    const float* Wi = (const float*)d_in[3];
    const float* bi = (const float*)d_in[4];
    const float* Wz = (const float*)d_in[5];
    const float* bz = (const float*)d_in[6];
    const float* Wo = (const float*)d_in[7];
    const float* bo = (const float*)d_in[8];
    const float* Wy = (const float*)d_in[9];
    const float* by = (const float*)d_in[10];
    float* out = (float*)d_out;

    char* ws = (char*)d_ws;
    const size_t XN = (size_t)2048 * 32 * 512 * sizeof(u16);  // 64 MB per gate array
    u16* Xi = (u16*)(ws);
    u16* Xz = (u16*)(ws + XN);
    u16* Xo = (u16*)(ws + 2 * XN);
    u32* WpkT = (u32*)(ws + 3 * XN);                            // 512 KB
    u32* Wypk = (u32*)(ws + 3 * XN + (size_t)524288);           // 512 KB
    u64* exch = (u64*)(ws + 3 * XN + (size_t)2 * 524288);       // 512 KB

    k0_pack<<<768, 256, 0, stream>>>(Wi, Wy, WpkT, Wypk);

    dim3 g1(1024, 4);
    k1_gates<<<g1, 256, 0, stream>>>(word, Wi, Wz, Wo, bi, bz, bo, Xi, Xz, Xo);

    k2_recur<<<64, 512, 0, stream>>>(Xi, Xz, Xo, WpkT, Wypk, exch, by, out);
}

// Round 8
// 4266.087 us; speedup vs baseline: 1.4002x; 1.0429x over previous
//
#include <hip/hip_runtime.h>

typedef unsigned int u32;
typedef unsigned short u16;
typedef unsigned long long u64;
typedef _Float16 f16;
typedef f16 f16x2 __attribute__((ext_vector_type(2)));

__device__ __forceinline__ float fdot2(u32 a, u32 b, float c) {
#if __has_builtin(__builtin_amdgcn_fdot2)
    return __builtin_amdgcn_fdot2(__builtin_bit_cast(f16x2, a),
                                  __builtin_bit_cast(f16x2, b), c, false);
#else
    f16x2 av = __builtin_bit_cast(f16x2, a), bv = __builtin_bit_cast(f16x2, b);
    c += (float)av[0] * (float)bv[0];
    c += (float)av[1] * (float)bv[1];
    return c;
#endif
}

__device__ __forceinline__ u32 pack2h(float a, float b) {
    f16x2 h; h[0] = (f16)a; h[1] = (f16)b;
    return __builtin_bit_cast(u32, h);
}
__device__ __forceinline__ float h2f(u16 x) { return (float)__builtin_bit_cast(f16, x); }
__device__ __forceinline__ u16 f2h(float x) { f16 h = (f16)x; return __builtin_bit_cast(u16, h); }

__device__ __forceinline__ float fexp(float x) {
#if __has_builtin(__builtin_amdgcn_exp2f)
    return __builtin_amdgcn_exp2f(x * 1.44269504088896f);
#else
    return __expf(x);
#endif
}
__device__ __forceinline__ float frcp(float x) {
#if __has_builtin(__builtin_amdgcn_rcpf)
    return __builtin_amdgcn_rcpf(x);
#else
    return 1.0f / x;
#endif
}
__device__ __forceinline__ float fsigmoid(float x) { return frcp(1.0f + fexp(-x)); }
__device__ __forceinline__ float ftanh_pos(float x) { return 1.0f - 2.0f * frcp(fexp(2.0f * x) + 1.0f); }

// Fast-path 8B exchange ops: sc0 bypasses L1, is L2-coherent (same-XCD only).
__device__ __forceinline__ u64 load_l2(const u64* p) {
    u64 v;
    asm volatile("global_load_dwordx2 %0, %1, off sc0\n\ts_waitcnt vmcnt(0)"
                 : "=v"(v) : "v"(p) : "memory");
    return v;
}
__device__ __forceinline__ void store_l2(u64* p, u64 v) {
    asm volatile("global_store_dwordx2 %0, %1, off sc0" :: "v"(p), "v"(v) : "memory");
}

// ---------------------------------------------------------------------------
// K0: pack weights to f16 pairs.
//   WpkT[d][p] = (Wi[d][2p], Wi[d][2p+1])   d<512, p<256   (row-major rows)
//   Wypk[p][d] = (Wy[d][2p], Wy[d][2p+1])   (K2 epilogue layout)
// ---------------------------------------------------------------------------
__global__ __launch_bounds__(256) void k0_pack(const float* __restrict__ Wi,
                                               const float* __restrict__ Wy,
                                               u32* __restrict__ WpkT,
                                               u32* __restrict__ Wypk) {
    const int bx = blockIdx.x, tid = threadIdx.x;
    if (bx < 512) {
        const float2 v = *(const float2*)(Wi + (size_t)bx * 512 + 2 * tid);
        WpkT[(size_t)bx * 256 + tid] = pack2h(v.x, v.y);
    } else {
        const int p = bx - 512;
        #pragma unroll
        for (int r = 0; r < 2; ++r) {
            const int d = tid + 256 * r;
            Wypk[(size_t)p * 512 + d] =
                pack2h(Wy[(size_t)d * 512 + 2 * p], Wy[(size_t)d * 512 + 2 * p + 1]);
        }
    }
}

// ---------------------------------------------------------------------------
// K1: gate pre-activations (parallel over all t). Unchanged.
// ---------------------------------------------------------------------------
__global__ __launch_bounds__(256) void k1_gates(
    const float* __restrict__ word,
    const float* __restrict__ Wi, const float* __restrict__ Wz, const float* __restrict__ Wo,
    const float* __restrict__ bi, const float* __restrict__ bz, const float* __restrict__ bo,
    u16* __restrict__ Xi, u16* __restrict__ Xz, u16* __restrict__ Xo)
{
    __shared__ uint4 ws2v[3][128][4];
    __shared__ u32 xs2[2][16][36];

    const int tid = threadIdx.x;
    const int d_l = tid & 63;
    const int bq  = tid >> 6;
    const int t0  = blockIdx.x * 2;
    const int d0  = blockIdx.y * 128;

    const float* Wg[3] = {Wi, Wz, Wo};

    float acc[2][2][8][3];
    #pragma unroll
    for (int tt = 0; tt < 2; ++tt)
        #pragma unroll
        for (int db = 0; db < 2; ++db)
            #pragma unroll
            for (int j = 0; j < 8; ++j)
                #pragma unroll
                for (int g = 0; g < 3; ++g) acc[tt][db][j][g] = 0.0f;

    for (int k0c = 0; k0c < 512; k0c += 32) {
        {
            const int p = tid & 15, bg = tid >> 4;
            #pragma unroll
            for (int tt = 0; tt < 2; ++tt)
                #pragma unroll
                for (int j = 0; j < 2; ++j) {
                    const int bb = bg * 2 + j;
                    const float2 v = *(const float2*)(word + (((size_t)(t0 + tt) * 32 + bb) * 512 + k0c + 2 * p));
                    xs2[tt][p][bb] = pack2h(v.x, v.y);
                }
        }
        {
            #pragma unroll
            for (int cc = 0; cc < 6; ++cc) {
                const int c = tid + 256 * cc;
                const int g = c >> 9, r = c & 511, pg = r >> 7, i = r & 127;
                const float* src = Wg[g] + (size_t)(d0 + i) * 512 + k0c + 8 * pg;
                const float4 v0 = ((const float4*)src)[0];
                const float4 v1 = ((const float4*)src)[1];
                uint4 cell;
                cell.x = pack2h(v0.x, v0.y); cell.y = pack2h(v0.z, v0.w);
                cell.z = pack2h(v1.x, v1.y); cell.w = pack2h(v1.z, v1.w);
                ws2v[g][i][(pg + (i >> 2)) & 3] = cell;
            }
        }
        __syncthreads();
        #pragma unroll
        for (int pg = 0; pg < 4; ++pg) {
            uint4 wc[3][2];
            #pragma unroll
            for (int g = 0; g < 3; ++g)
                #pragma unroll
                for (int db = 0; db < 2; ++db) {
                    const int d = d_l + 64 * db;
                    wc[g][db] = ws2v[g][d][(pg + (d >> 2)) & 3];
                }
            #pragma unroll
            for (int p = 0; p < 4; ++p) {
                const int pair = 4 * pg + p;
                u32 x2[2][8];
                #pragma unroll
                for (int tt = 0; tt < 2; ++tt) {
                    const uint4* xr = (const uint4*)&xs2[tt][pair][bq * 8];
                    uint4 xa = xr[0], xb = xr[1];
                    x2[tt][0] = xa.x; x2[tt][1] = xa.y; x2[tt][2] = xa.z; x2[tt][3] = xa.w;
                    x2[tt][4] = xb.x; x2[tt][5] = xb.y; x2[tt][6] = xb.z; x2[tt][7] = xb.w;
                }
                u32 w[3][2];
                #pragma unroll
                for (int g = 0; g < 3; ++g)
                    #pragma unroll
                    for (int db = 0; db < 2; ++db) {
                        const uint4 v = wc[g][db];
                        w[g][db] = (p == 0) ? v.x : (p == 1) ? v.y : (p == 2) ? v.z : v.w;
                    }
                #pragma unroll
                for (int tt = 0; tt < 2; ++tt)
                    #pragma unroll
                    for (int db = 0; db < 2; ++db)
                        #pragma unroll
                        for (int j = 0; j < 8; ++j)
                            #pragma unroll
                            for (int g = 0; g < 3; ++g)
                                acc[tt][db][j][g] = fdot2(x2[tt][j], w[g][db], acc[tt][db][j][g]);
            }
        }
        __syncthreads();
    }

    #pragma unroll
    for (int db = 0; db < 2; ++db) {
        const int d = d0 + 64 * db + d_l;
        const float b0 = 2.0f * bi[d];
        const float b1 = bz[d] + bi[d];
        const float b2 = bo[d] + bi[d];
        #pragma unroll
        for (int tt = 0; tt < 2; ++tt)
            #pragma unroll
            for (int j = 0; j < 8; ++j) {
                const size_t o = ((size_t)(t0 + tt) * 32 + (bq * 8 + j)) * 512 + d;
                Xi[o] = f2h(acc[tt][db][j][0] + b0);
                Xz[o] = f2h(acc[tt][db][j][1] + b1);
                Xo[o] = f2h(acc[tt][db][j][2] + b2);
            }
    }
}

// ---------------------------------------------------------------------------
// K2 v4: K-split recurrence, 2 WGs per batch element (partner = bid ^ 8,
// same XCD under round-robin dispatch).
// Exchange protocol (stateless, deadlock-free): every step each thread posts
// {p, tag=t+1} to BOTH a fast slot (sc0 store -> own/partner shared L2 when
// same-XCD) and a slow slot (agent-scope atomic -> IC, the round-6 proven
// path). The wait loop ALTERNATES fast and slow loads each iteration, so a
// stale-L2 fast slot can never wedge us: the slow load always sees the truth.
// Tag rides with data in one aligned 8B access (HW-atomic); parity-2 slots
// make reuse race-free; poisoned 0xAA tags never match tags 1..2048.
// Weights: 128 u32/thread pinned in VGPRs via opaque asm (round 6 showed the
// compiler otherwise re-streams 512 KB/WG/step from L2: VGPR_Count=84).
// ---------------------------------------------------------------------------
__global__ __launch_bounds__(512, 2) void k2_recur(
    const u16* __restrict__ Xi, const u16* __restrict__ Xz, const u16* __restrict__ Xo,
    const u32* __restrict__ WpkT, const u32* __restrict__ Wypk,
    u64* __restrict__ exchF, u64* __restrict__ exchS,
    const float* __restrict__ by, float* __restrict__ out)
{
    __shared__ alignas(16) u16 hb[2][256];   // own K-half of h, f16, ping-pong
    __shared__ alignas(16) u16 hfull[512];   // final h for the epilogue

    const int bid  = blockIdx.x;
    const int half = (bid >> 3) & 1;                    // partner = bid ^ 8
    const int b    = (bid & 7) | ((bid >> 4) << 3);     // 0..31
    const int tid  = threadIdx.x;                       // = output dim d

    // weight slice: output d=tid, K-pairs [128*half, 128*half+128)
    const uint4* WpkT4 = (const uint4*)WpkT;
    u32 wq[128];
    #pragma unroll
    for (int i = 0; i < 32; ++i) {
        const uint4 v = WpkT4[(size_t)tid * 64 + half * 32 + i];
        wq[4 * i + 0] = v.x; wq[4 * i + 1] = v.y;
        wq[4 * i + 2] = v.z; wq[4 * i + 3] = v.w;
    }
    #pragma unroll
    for (int i = 0; i < 128; ++i) asm volatile("" : "+v"(wq[i]));  // pin in VGPRs

    if (tid < 256) hb[0][tid] = (u16)0;      // h = 0 at t = 0
    __syncthreads();

    const size_t me  = (size_t)(b * 2 + half) * 2 * 512 + tid;
    const size_t pa  = (size_t)(b * 2 + (half ^ 1)) * 2 * 512 + tid;
    u64* eoF = exchF + me;  u64* eoS = exchS + me;
    const u64* eiF = exchF + pa;  const u64* eiS = exchS + pa;

    const int ownhalf = ((tid >> 8) == half);
    const int hloc = tid & 255;

    u16 xi_c = Xi[(size_t)b * 512 + tid];
    u16 xz_c = Xz[(size_t)b * 512 + tid];
    u16 xo_c = Xo[(size_t)b * 512 + tid];

    float hn = 0.0f;
    for (int t = 0; t < 2048; ++t) {
        const int par = t & 1;
        const int tn = (t + 1) & 2047;
        const size_t xb = ((size_t)tn * 32 + b) * 512 + tid;
        const u16 xi_n = Xi[xb], xz_n = Xz[xb], xo_n = Xo[xb];

        // partial dot over own K-half (h broadcast from LDS, weights in VGPRs)
        const uint4* hv = (const uint4*)&hb[par][0];
        float a0 = 0.f, a1 = 0.f, a2 = 0.f, a3 = 0.f;
        #pragma unroll
        for (int i = 0; i < 32; ++i) {
            const uint4 hc = hv[i];
            a0 = fdot2(hc.x, wq[4 * i + 0], a0);
            a1 = fdot2(hc.y, wq[4 * i + 1], a1);
            a2 = fdot2(hc.z, wq[4 * i + 2], a2);
            a3 = fdot2(hc.w, wq[4 * i + 3], a3);
        }
        const float p = (a0 + a1) + (a2 + a3);

        // post {p, tag} to BOTH slots
        const u32 tag = (u32)(t + 1);
        const u64 msg = ((u64)tag << 32) | (u64)__builtin_bit_cast(u32, p);
        store_l2(eoF + (size_t)par * 512, msg);
        __hip_atomic_store(eoS + (size_t)par * 512, msg,
                           __ATOMIC_RELAXED, __HIP_MEMORY_SCOPE_AGENT);

        // stateless alternating poll: fast (L2) then slow (IC), repeat
        u64 m;
        for (;;) {
            m = load_l2(eiF + (size_t)par * 512);
            if ((u32)(m >> 32) == tag) break;
            m = __hip_atomic_load(eiS + (size_t)par * 512,
                                  __ATOMIC_RELAXED, __HIP_MEMORY_SCOPE_AGENT);
            if ((u32)(m >> 32) == tag) break;
        }
        const float v = p + __builtin_bit_cast(float, (u32)m);

        const float zi = fsigmoid(h2f(xi_c) + v);
        const float z  = fsigmoid(h2f(xz_c) + v);
        const float zo = fsigmoid(h2f(xo_c) + v);
        hn = zo * ftanh_pos(zi * z);

        if (ownhalf) hb[par ^ 1][hloc] = f2h(hn);
        __syncthreads();

        xi_c = xi_n; xz_c = xz_n; xo_c = xo_n;
    }

    // epilogue: both WGs redundantly compute identical out[b,:]
    hfull[tid] = f2h(hn);
    __syncthreads();
    {
        const uint4* hv = (const uint4*)&hfull[0];
        float e0 = 0.f, e1 = 0.f, e2 = 0.f, e3 = 0.f;
        #pragma unroll 8
        for (int i = 0; i < 64; ++i) {
            const uint4 hc = hv[i];
            e0 = fdot2(hc.x, Wypk[(size_t)(4 * i + 0) * 512 + tid], e0);
            e1 = fdot2(hc.y, Wypk[(size_t)(4 * i + 1) * 512 + tid], e1);
            e2 = fdot2(hc.z, Wypk[(size_t)(4 * i + 2) * 512 + tid], e2);
            e3 = fdot2(hc.w, Wypk[(size_t)(4 * i + 3) * 512 + tid], e3);
        }
        out[(size_t)b * 512 + tid] = (e0 + e1) + (e2 + e3) + by[tid];
    }
}

// ---------------------------------------------------------------------------
extern "C" void kernel_launch(void* const* d_in, const int* in_sizes, int n_in,
                              void* d_out, int out_size, void* d_ws, size_t ws_size,
                              hipStream_t stream) {
    const float* word = (const float*)d_in[0];
    // d_in[1]=Wf, d_in[2]=bf : dead in the reference (c==0 path), unused.
    const float* Wi = (const float*)d_in[3];
    const float* bi = (const float*)d_in[4];
    const float* Wz = (const float*)d_in[5];
    const float* bz = (const float*)d_in[6];
    const float* Wo = (const float*)d_in[7];
    const float* bo = (const float*)d_in[8];
    const float* Wy = (const float*)d_in[9];
    const float* by = (const float*)d_in[10];
    float* out = (float*)d_out;

    char* ws = (char*)d_ws;
    const size_t XN = (size_t)2048 * 32 * 512 * sizeof(u16);  // 64 MB per gate array
    u16* Xi = (u16*)(ws);
    u16* Xz = (u16*)(ws + XN);
    u16* Xo = (u16*)(ws + 2 * XN);
    u32* WpkT  = (u32*)(ws + 3 * XN);                           // 512 KB
    u32* Wypk  = (u32*)(ws + 3 * XN + (size_t)524288);          // 512 KB
    u64* exchF = (u64*)(ws + 3 * XN + (size_t)2 * 524288);      // 512 KB
    u64* exchS = (u64*)(ws + 3 * XN + (size_t)3 * 524288);      // 512 KB

    k0_pack<<<768, 256, 0, stream>>>(Wi, Wy, WpkT, Wypk);

    dim3 g1(1024, 4);
    k1_gates<<<g1, 256, 0, stream>>>(word, Wi, Wz, Wo, bi, bz, bo, Xi, Xz, Xo);

    k2_recur<<<64, 512, 0, stream>>>(Xi, Xz, Xo, WpkT, Wypk, exchF, exchS, by, out);
}